// Round 2
// baseline (308.749 us; speedup 1.0000x reference)
//
#include <hip/hip_runtime.h>
#include <stdint.h>

typedef unsigned short ushort_t;
typedef __attribute__((ext_vector_type(8))) short short8;
typedef __attribute__((ext_vector_type(8))) _Float16 half8;
typedef __attribute__((ext_vector_type(4))) float f32x4;
typedef __attribute__((ext_vector_type(4))) unsigned short us4;

#define AS1 __attribute__((address_space(1)))
#define AS3 __attribute__((address_space(3)))

#if __has_builtin(__builtin_amdgcn_exp2f)
#define EXP2(x) __builtin_amdgcn_exp2f(x)
#else
#define EXP2(x) exp2f(x)
#endif

// scores are multiplied by 8 (the reference's /scale bug); fold into exp2 base
#define SC 11.541560327111707f  // 8 * log2(e)

__device__ __forceinline__ ushort_t f2h(float f) {
  _Float16 h = (_Float16)f;   // v_cvt_f16_f32, RNE
  return __builtin_bit_cast(unsigned short, h);
}

__device__ __forceinline__ void gload16(const void* g, void* l) {
  __builtin_amdgcn_global_load_lds((AS1 const void*)g, (AS3 void*)l, 16, 0, 0);
}

__device__ __forceinline__ f32x4 mfma16(short8 a, short8 b, f32x4 c) {
  return __builtin_amdgcn_mfma_f32_16x16x32_f16(
      __builtin_bit_cast(half8, a), __builtin_bit_cast(half8, b), c, 0, 0, 0);
}

// ---------------- cast x fp32 -> fp16 ----------------
__global__ __launch_bounds__(256) void cast_f32_f16(const float4* __restrict__ in,
                                                    us4* __restrict__ out, int n4) {
  int i = blockIdx.x * 256 + threadIdx.x;
  int stride = gridDim.x * 256;
  for (; i < n4; i += stride) {
    float4 v = in[i];
    us4 o;
    o[0] = f2h(v.x); o[1] = f2h(v.y); o[2] = f2h(v.z); o[3] = f2h(v.w);
    out[i] = o;
  }
}

// ---------------- transpose-cast W [R][C] fp32 -> Wt [C][R] fp16 ----------------
__global__ __launch_bounds__(256) void tcast(const float* __restrict__ in,
                                             ushort_t* __restrict__ out, int R, int C) {
  __shared__ __align__(16) float lt[32][33];
  const int r0 = blockIdx.y * 32, c0 = blockIdx.x * 32;
  const int i = threadIdx.x;
  const int lr = i >> 3, lc = (i & 7) * 4;
  float4 v = *(const float4*)(in + (size_t)(r0 + lr) * C + c0 + lc);
  lt[lr][lc + 0] = v.x; lt[lr][lc + 1] = v.y; lt[lr][lc + 2] = v.z; lt[lr][lc + 3] = v.w;
  __syncthreads();
  const int oc = i >> 3;          // out row (a column c of in)
  const int orr = (i & 7) * 4;    // out col (row r of in)
  us4 o;
#pragma unroll
  for (int jj = 0; jj < 4; ++jj) o[jj] = f2h(lt[orr + jj][oc]);
  *(us4*)(out + (size_t)(c0 + oc) * R + r0 + orr) = o;
}

// ---------------- 128x128 fp16 GEMM, BK=64, A[M][K] x Bt[N][K] ----------------
// MODE 0: epilogue scatters into q/k/v head layouts (fp16)
// MODE 1: epilogue writes fp32 out[M][N]
template<int MODE>
__global__ __launch_bounds__(256) void gemm128(
    const ushort_t* __restrict__ A, const ushort_t* __restrict__ Bt, int K, int N,
    ushort_t* __restrict__ qo, ushort_t* __restrict__ ko, ushort_t* __restrict__ vo,
    float* __restrict__ outp)
{
  __shared__ __align__(16) unsigned char lds[32768];   // A tile 16K, B tile 16K
  const int tid = threadIdx.x;
  const int lane = tid & 63, w = tid >> 6;
  const int ln = lane & 15, gq = lane >> 4;
  const int wr = w >> 1, wc = w & 1;
  const int m0 = blockIdx.y * 128, n0 = blockIdx.x * 128;
  const size_t ldb = (size_t)K * 2;  // row bytes
  const unsigned char* ab = (const unsigned char*)A + (size_t)m0 * ldb;
  const unsigned char* bb = (const unsigned char*)Bt + (size_t)n0 * ldb;
  f32x4 acc[4][4] = {};
  const int nkt = K >> 6;
  for (int kb = 0; kb < nkt; ++kb) {
    const unsigned char* abk = ab + kb * 128;
    const unsigned char* bbk = bb + kb * 128;
#pragma unroll
    for (int e = 0; e < 4; ++e) {
      unsigned o = e * 4096 + tid * 16;
      unsigned r = o >> 7;
      unsigned c = (o & 127) ^ ((r & 7) << 4);   // pre-swizzled source
      gload16(abk + (size_t)r * ldb + c, lds + o);
      gload16(bbk + (size_t)r * ldb + c, lds + 16384 + o);
    }
    __syncthreads();
    short8 af[4][2], bf8[4][2];
#pragma unroll
    for (int mi = 0; mi < 4; ++mi) {
      unsigned row = wr * 64 + mi * 16 + ln;
      unsigned c0 = (gq * 16) ^ ((row & 7) << 4);
      af[mi][0] = *(const short8*)(lds + row * 128 + c0);
      af[mi][1] = *(const short8*)(lds + row * 128 + (c0 ^ 64));
    }
#pragma unroll
    for (int ni = 0; ni < 4; ++ni) {
      unsigned row = wc * 64 + ni * 16 + ln;
      unsigned c0 = (gq * 16) ^ ((row & 7) << 4);
      bf8[ni][0] = *(const short8*)(lds + 16384 + row * 128 + c0);
      bf8[ni][1] = *(const short8*)(lds + 16384 + row * 128 + (c0 ^ 64));
    }
#pragma unroll
    for (int mi = 0; mi < 4; ++mi)
#pragma unroll
      for (int ni = 0; ni < 4; ++ni) {
        acc[mi][ni] = mfma16(af[mi][0], bf8[ni][0], acc[mi][ni]);
        acc[mi][ni] = mfma16(af[mi][1], bf8[ni][1], acc[mi][ni]);
      }
    __syncthreads();
  }
  // epilogue: D layout col = lane&15, row = (lane>>4)*4 + j
  if (MODE == 0) {
#pragma unroll
    for (int mi = 0; mi < 4; ++mi)
#pragma unroll
      for (int ni = 0; ni < 4; ++ni)
#pragma unroll
        for (int j = 0; j < 4; ++j) {
          int token = m0 + wr * 64 + mi * 16 + gq * 4 + j;
          int feat  = n0 + wc * 64 + ni * 16 + ln;
          int sec = feat >> 10, cc = feat & 1023;
          int hh = cc >> 6, dd = cc & 63;
          size_t off = (((size_t)(token >> 11) * 16 + hh) * 2048 + (token & 2047)) * 64 + dd;
          ushort_t valb = f2h(acc[mi][ni][j]);
          if (sec == 0) qo[off] = valb;
          else if (sec == 1) ko[off] = valb;
          else vo[off] = valb;
        }
  } else {
#pragma unroll
    for (int mi = 0; mi < 4; ++mi)
#pragma unroll
      for (int ni = 0; ni < 4; ++ni)
#pragma unroll
        for (int j = 0; j < 4; ++j) {
          int token = m0 + wr * 64 + mi * 16 + gq * 4 + j;
          int feat  = n0 + wc * 64 + ni * 16 + ln;
          outp[(size_t)token * N + feat] = acc[mi][ni][j];
        }
  }
}

// ---------------- V [bh][2048][64] -> Vt [bh][64][2048] ----------------
__global__ __launch_bounds__(256) void transpose_v(const ushort_t* __restrict__ vn,
                                                   ushort_t* __restrict__ vt) {
  __shared__ __align__(16) ushort_t lt[64][80];
  const int bh = blockIdx.y, t0 = blockIdx.x * 64;
  const int i = threadIdx.x;
  {
    const int tr = i >> 2, dc = (i & 3) * 16;
    const ushort_t* src = vn + ((size_t)bh * 2048 + t0 + tr) * 64 + dc;
    *(short8*)&lt[tr][dc] = *(const short8*)src;
    *(short8*)&lt[tr][dc + 8] = *(const short8*)(src + 8);
  }
  __syncthreads();
  {
    const int dr = i >> 2, tc = (i & 3) * 16;
    short8 a, b;
#pragma unroll
    for (int jj = 0; jj < 8; ++jj) a[jj] = (short)lt[tc + jj][dr];
#pragma unroll
    for (int jj = 0; jj < 8; ++jj) b[jj] = (short)lt[tc + 8 + jj][dr];
    ushort_t* dst = vt + ((size_t)bh * 64 + dr) * 2048 + t0 + tc;
    *(short8*)dst = a;
    *(short8*)(dst + 8) = b;
  }
}

// ---------------- flash attention: block = (qb, bh), 4 waves x 16 q-rows ----------------
__global__ __launch_bounds__(256) void attn_kernel(const ushort_t* __restrict__ qg,
                                                   const ushort_t* __restrict__ kg,
                                                   const ushort_t* __restrict__ vtg,
                                                   ushort_t* __restrict__ yg) {
  __shared__ __align__(16) unsigned char lds[24576]; // Ks @0 (8K), Vts @8192 (8K), Ps @16384 (4x2K)
  const int qb = blockIdx.x;         // 0..31
  const int bh = blockIdx.y;         // 0..63
  const int tid = threadIdx.x;
  const int lane = tid & 63, w = tid >> 6;
  const int ln = lane & 15, gq = lane >> 4;
  const int q0 = qb * 64;

  // Q fragments (A-operand): row = lane&15, d = step*32 + gq*8 + j
  const ushort_t* qrow = qg + ((size_t)bh * 2048 + q0 + w * 16 + ln) * 64;
  short8 qa0 = *(const short8*)(qrow + gq * 8);
  short8 qa1 = *(const short8*)(qrow + 32 + gq * 8);

  f32x4 yacc[4] = {};
  float mrow[4] = {-3e38f, -3e38f, -3e38f, -3e38f};
  float lrow[4] = {0.f, 0.f, 0.f, 0.f};

  const unsigned char* kbase0 = (const unsigned char*)kg + (size_t)bh * 2048 * 128;
  const unsigned char* vbase0 = (const unsigned char*)vtg + (size_t)bh * 64 * 4096;

  for (int kb = 0; kb <= qb; ++kb) {
    // stage K tile [64 kv][64 d] (contiguous 8KB in global) and Vt tile [64 d][64 kv]
    const unsigned char* kt = kbase0 + (size_t)kb * 8192;
    const unsigned char* vt = vbase0 + kb * 128;
#pragma unroll
    for (int e = 0; e < 2; ++e) {
      unsigned o = e * 4096 + tid * 16;
      unsigned r = o >> 7;
      unsigned c = (o & 127) ^ ((r & 7) << 4);
      gload16(kt + r * 128 + c, lds + o);
      gload16(vt + (size_t)r * 4096 + c, lds + 8192 + o);
    }
    __syncthreads();

    // scores: S[16 q][64 kv] in 4 fragments
    f32x4 s[4];
#pragma unroll
    for (int f = 0; f < 4; ++f) {
      unsigned row = f * 16 + ln;                   // kv row in K tile
      unsigned c0 = (gq * 16) ^ ((row & 7) << 4);
      short8 k0 = *(const short8*)(lds + row * 128 + c0);
      short8 k1 = *(const short8*)(lds + row * 128 + (c0 ^ 64));
      f32x4 z = {0.f, 0.f, 0.f, 0.f};
      z = mfma16(qa0, k0, z);
      s[f] = mfma16(qa1, k1, z);
    }
    if (kb == qb) {  // diagonal block: mask kv > q
#pragma unroll
      for (int f = 0; f < 4; ++f) {
        int kvloc = f * 16 + ln;
#pragma unroll
        for (int j = 0; j < 4; ++j) {
          int qloc = w * 16 + gq * 4 + j;
          if (kvloc > qloc) s[f][j] = -3e38f;
        }
      }
    }
    // online softmax per row j (row held by 16 lanes of group gq, col = ln)
#pragma unroll
    for (int j = 0; j < 4; ++j) {
      float rm = fmaxf(fmaxf(s[0][j], s[1][j]), fmaxf(s[2][j], s[3][j]));
      rm = fmaxf(rm, __shfl_xor(rm, 1));
      rm = fmaxf(rm, __shfl_xor(rm, 2));
      rm = fmaxf(rm, __shfl_xor(rm, 4));
      rm = fmaxf(rm, __shfl_xor(rm, 8));
      float mnew = fmaxf(mrow[j], rm);
      float alpha = EXP2((mrow[j] - mnew) * SC);
      float rs = 0.f;
#pragma unroll
      for (int f = 0; f < 4; ++f) {
        float p = EXP2((s[f][j] - mnew) * SC);
        s[f][j] = p;
        rs += p;
      }
      rs += __shfl_xor(rs, 1);
      rs += __shfl_xor(rs, 2);
      rs += __shfl_xor(rs, 4);
      rs += __shfl_xor(rs, 8);
      lrow[j] = lrow[j] * alpha + rs;
      mrow[j] = mnew;
#pragma unroll
      for (int df = 0; df < 4; ++df) yacc[df][j] *= alpha;
    }
    // write P (fp16) into per-wave swizzled LDS buffer [16 q][64 kv]
    {
      unsigned pw = 16384 + w * 2048;
#pragma unroll
      for (int f = 0; f < 4; ++f)
#pragma unroll
        for (int j = 0; j < 4; ++j) {
          unsigned row = gq * 4 + j;
          unsigned addr = (pw + row * 128 + (f * 16 + ln) * 2) ^ ((row & 7) << 4);
          *(ushort_t*)(lds + addr) = f2h(s[f][j]);
        }
    }
    __syncthreads();   // order P writes before A-layout reads (and keep waves together)
    // PV: y[16 q][64 d] += P[16 q][64 kv] * V[64 kv][64 d]
    {
      unsigned pw = 16384 + w * 2048;
#pragma unroll
      for (int st = 0; st < 2; ++st) {
        unsigned pc = (st * 64 + gq * 16) ^ ((ln & 7) << 4);
        short8 pa = *(const short8*)(lds + pw + ln * 128 + pc);
#pragma unroll
        for (int df = 0; df < 4; ++df) {
          unsigned row = df * 16 + ln;               // d row in Vt tile
          unsigned c0 = (st * 64 + gq * 16) ^ ((row & 7) << 4);
          short8 vb = *(const short8*)(lds + 8192 + row * 128 + c0);
          yacc[df] = mfma16(pa, vb, yacc[df]);
        }
      }
    }
    __syncthreads();   // protect K/Vt tiles before next staging
  }
  // epilogue: y[b][t][h*64+d] fp16
#pragma unroll
  for (int df = 0; df < 4; ++df)
#pragma unroll
    for (int j = 0; j < 4; ++j) {
      int t = q0 + w * 16 + gq * 4 + j;
      int col = (bh & 15) * 64 + df * 16 + ln;
      size_t off = ((size_t)(bh >> 4) * 2048 + t) * 1024 + col;
      yg[off] = f2h(yacc[df][j] / lrow[j]);
    }
}

extern "C" void kernel_launch(void* const* d_in, const int* in_sizes, int n_in,
                              void* d_out, int out_size, void* d_ws, size_t ws_size,
                              hipStream_t stream) {
  (void)in_sizes; (void)n_in; (void)out_size; (void)ws_size;
  const float* x     = (const float*)d_in[0];
  const float* wqkv  = (const float*)d_in[1];
  const float* wproj = (const float*)d_in[2];
  float* out = (float*)d_out;
  char* ws = (char*)d_ws;
  // ws layout (bytes)
  ushort_t* xb   = (ushort_t*)(ws);               // 16MB  (reused as y after QKV GEMM)
  ushort_t* wqkt = (ushort_t*)(ws + 16777216);    // 6MB
  ushort_t* wpt  = (ushort_t*)(ws + 23068672);    // 2MB
  ushort_t* qb_  = (ushort_t*)(ws + 25165824);    // 16MB [bh][t][d]
  ushort_t* kb_  = (ushort_t*)(ws + 41943040);    // 16MB [bh][t][d]
  ushort_t* vn   = (ushort_t*)(ws + 58720256);    // 16MB [bh][t][d]
  ushort_t* vt   = (ushort_t*)(ws + 75497472);    // 16MB [bh][d][t]
  ushort_t* yb   = xb;

  cast_f32_f16<<<2048, 256, 0, stream>>>((const float4*)x, (us4*)xb, 2097152);
  tcast<<<dim3(96, 32), 256, 0, stream>>>(wqkv, wqkt, 1024, 3072);
  tcast<<<dim3(32, 32), 256, 0, stream>>>(wproj, wpt, 1024, 1024);
  gemm128<0><<<dim3(24, 64), 256, 0, stream>>>(xb, wqkt, 1024, 3072, qb_, kb_, vn, nullptr);
  transpose_v<<<dim3(32, 64), 256, 0, stream>>>(vn, vt);
  attn_kernel<<<dim3(32, 64), 256, 0, stream>>>(qb_, kb_, vt, yb);
  gemm128<1><<<dim3(8, 64), 256, 0, stream>>>(yb, wpt, 1024, 1024, nullptr, nullptr, nullptr, out);
}